// Round 17
// baseline (111.019 us; speedup 1.0000x reference)
//
#include <hip/hip_runtime.h>
#include <stdint.h>

typedef __attribute__((ext_vector_type(8))) short short8;
typedef __attribute__((ext_vector_type(4))) short short4v;
typedef __attribute__((ext_vector_type(4))) float f32x4;

__device__ __forceinline__ short f2bf(float x) {
  union { float f; uint32_t u; } c; c.f = x;
  uint32_t r = (c.u + 0x7FFFu + ((c.u >> 16) & 1u)) >> 16;
  return (short)r;
}
__device__ __forceinline__ float b2f(short s) {
  union { uint32_t u; float f; } c; c.u = ((uint32_t)(uint16_t)s) << 16;
  return c.f;
}
__device__ __forceinline__ uint32_t pack2bf(float lo, float hi) {
  return ((uint32_t)(uint16_t)f2bf(hi) << 16) | (uint32_t)(uint16_t)f2bf(lo);
}

// ============ merged prep: cvt(x) + tcvt(Wqkv) + tcvt(Wout) ============
__global__ __launch_bounds__(256) void prep_kernel(const float* __restrict__ x,
                                                   const float* __restrict__ Wqkv,
                                                   const float* __restrict__ Wout,
                                                   short* __restrict__ xb,
                                                   short* __restrict__ wqkvT,
                                                   short* __restrict__ woutT) {
  __shared__ __align__(16) short tile[32][33];
  const int bid = blockIdx.x;
  if (bid < 2048) {
    const int n4 = (4 * 1024 * 1024) / 4;
    int i = bid * 256 + threadIdx.x;
    for (; i < n4; i += 2048 * 256) {
      float4 v = reinterpret_cast<const float4*>(x)[i];
      short4v o;
      o.x = f2bf(v.x); o.y = f2bf(v.y); o.z = f2bf(v.z); o.w = f2bf(v.w);
      reinterpret_cast<short4v*>(xb)[i] = o;
    }
  } else {
    const float* in;
    short* out;
    int K, N, bx, by;
    if (bid < 2048 + 3072) {
      const int idx = bid - 2048;
      in = Wqkv; out = wqkvT; K = 1024; N = 3072; bx = idx % 96; by = idx / 96;
    } else {
      const int idx = bid - 5120;
      in = Wout; out = woutT; K = 1024; N = 1024; bx = idx % 32; by = idx / 32;
    }
    const int nb = bx * 32, kb = by * 32;
    const int tx = threadIdx.x & 31, ty = threadIdx.x >> 5; // 32 x 8
#pragma unroll
    for (int i = 0; i < 32; i += 8)
      tile[ty + i][tx] = f2bf(in[(size_t)(kb + ty + i) * N + nb + tx]);
    __syncthreads();
#pragma unroll
    for (int i = 0; i < 32; i += 8)
      out[(size_t)(nb + ty + i) * K + kb + tx] = tile[tx][ty + i];
  }
}

// ============ vtrans: qkv[b][kv][2048+c] -> vT[b][c][kv] ============
__global__ __launch_bounds__(256) void vtrans_kernel(const short* __restrict__ qkvb,
                                                     short* __restrict__ vT) {
  __shared__ __align__(16) short tile[64][65];
  const int bid = blockIdx.x;
  const int b = bid / 256;
  const int kv0 = (bid % 16) * 64, c0 = ((bid / 16) % 16) * 64;
  const int tx = threadIdx.x & 15, ty = threadIdx.x >> 4; // 16 x 16
  const short* src = qkvb + (size_t)(b * 1024) * 3072 + 2048;
#pragma unroll
  for (int i = 0; i < 64; i += 16) {
    int r = ty + i;
#pragma unroll
    for (int j = 0; j < 4; ++j)
      tile[r][tx * 4 + j] = src[(size_t)(kv0 + r) * 3072 + c0 + tx * 4 + j];
  }
  __syncthreads();
  short* dst = vT + (size_t)b * 1024 * 1024;
#pragma unroll
  for (int i = 0; i < 64; i += 16) {
    int cc = ty + i;
#pragma unroll
    for (int j = 0; j < 4; ++j)
      dst[(size_t)(c0 + cc) * 1024 + kv0 + tx * 4 + j] = tile[tx * 4 + j][cc];
  }
}

// ---------------- bf16 MFMA GEMM: C[M][N] = A[M][K] * Bt[N][K]^T (128^2) ----------------
template <int OUT_BF16>
__global__ __launch_bounds__(256) void gemm_kernel(const short* __restrict__ A,
                                                   const short* __restrict__ Bt,
                                                   void* __restrict__ Cout,
                                                   int K, int ldc) {
  __shared__ __align__(16) short Al[2][128 * 32];
  __shared__ __align__(16) short Bl[2][128 * 32];
  const int t = threadIdx.x;
  const int lane = t & 63, w = t >> 6;
  const int wr = w >> 1, wc = w & 1;
  const int g = lane >> 4, c16 = lane & 15;
  const int row0 = blockIdx.y * 128, col0 = blockIdx.x * 128;

  f32x4 acc[4][4];
#pragma unroll
  for (int m = 0; m < 4; ++m)
#pragma unroll
    for (int n = 0; n < 4; ++n) {
      f32x4 z = {0.0f, 0.0f, 0.0f, 0.0f};
      acc[m][n] = z;
    }

  auto stage = [&](int buf, int kt) {
    const int k0 = kt * 32;
#pragma unroll
    for (int i = 0; i < 2; ++i) {
      const int qb = i * 256 + (t & 192); // wave-uniform chunk base
      const int q = qb + lane;
      const int r = q >> 2;
      const int c = (q & 3) ^ ((r >> 1) & 3);
      const short* ga = A + (size_t)(row0 + r) * K + k0 + c * 8;
      const short* gb = Bt + (size_t)(col0 + r) * K + k0 + c * 8;
      __builtin_amdgcn_global_load_lds((const __attribute__((address_space(1))) void*)ga,
                                       (__attribute__((address_space(3))) void*)&Al[buf][qb * 8],
                                       16, 0, 0);
      __builtin_amdgcn_global_load_lds((const __attribute__((address_space(1))) void*)gb,
                                       (__attribute__((address_space(3))) void*)&Bl[buf][qb * 8],
                                       16, 0, 0);
    }
  };

  stage(0, 0);
  __syncthreads();
  const int NK = K >> 5;
  int cur = 0;
  const int rA0 = wr * 64 + c16;
  const int rB0 = wc * 64 + c16;
  for (int kt = 0; kt < NK; ++kt) {
    if (kt + 1 < NK) stage(cur ^ 1, kt + 1);
    short8 aF[4], bF[4];
#pragma unroll
    for (int m = 0; m < 4; ++m) {
      const int r = rA0 + m * 16;
      const int c = g ^ ((r >> 1) & 3);
      aF[m] = *reinterpret_cast<const short8*>(&Al[cur][r * 32 + c * 8]);
    }
#pragma unroll
    for (int n = 0; n < 4; ++n) {
      const int r = rB0 + n * 16;
      const int c = g ^ ((r >> 1) & 3);
      bF[n] = *reinterpret_cast<const short8*>(&Bl[cur][r * 32 + c * 8]);
    }
#pragma unroll
    for (int m = 0; m < 4; ++m)
#pragma unroll
      for (int n = 0; n < 4; ++n)
        acc[m][n] = __builtin_amdgcn_mfma_f32_16x16x32_bf16(aF[m], bF[n], acc[m][n], 0, 0, 0);
    __syncthreads();
    cur ^= 1;
  }

  const int er = row0 + wr * 64 + g * 4;
  const int ec = col0 + wc * 64 + c16;
#pragma unroll
  for (int m = 0; m < 4; ++m)
#pragma unroll
    for (int n = 0; n < 4; ++n)
#pragma unroll
      for (int j = 0; j < 4; ++j) {
        const size_t off = (size_t)(er + m * 16 + j) * ldc + ec + n * 16;
        if (OUT_BF16)
          ((short*)Cout)[off] = f2bf(acc[m][n][j]);
        else
          ((float*)Cout)[off] = acc[m][n][j];
      }
}

// ------------- bf16 MFMA GEMM: 128x64 tile (for small-N gemm2: 2x grid) -------------
template <int OUT_BF16>
__global__ __launch_bounds__(256) void gemm64_kernel(const short* __restrict__ A,
                                                     const short* __restrict__ Bt,
                                                     void* __restrict__ Cout,
                                                     int K, int ldc) {
  __shared__ __align__(16) short Al[2][128 * 32];
  __shared__ __align__(16) short Bl[2][64 * 32];
  const int t = threadIdx.x;
  const int lane = t & 63, w = t >> 6;
  const int wr = w >> 1, wc = w & 1;
  const int g = lane >> 4, c16 = lane & 15;
  const int row0 = blockIdx.y * 128, col0 = blockIdx.x * 64;

  f32x4 acc[4][2];
#pragma unroll
  for (int m = 0; m < 4; ++m)
#pragma unroll
    for (int n = 0; n < 2; ++n) {
      f32x4 z = {0.0f, 0.0f, 0.0f, 0.0f};
      acc[m][n] = z;
    }

  auto stage = [&](int buf, int kt) {
    const int k0 = kt * 32;
#pragma unroll
    for (int i = 0; i < 2; ++i) { // A: 512 chunks over 2 iters
      const int qb = i * 256 + (t & 192);
      const int q = qb + lane;
      const int r = q >> 2;
      const int c = (q & 3) ^ ((r >> 1) & 3);
      const short* ga = A + (size_t)(row0 + r) * K + k0 + c * 8;
      __builtin_amdgcn_global_load_lds((const __attribute__((address_space(1))) void*)ga,
                                       (__attribute__((address_space(3))) void*)&Al[buf][qb * 8],
                                       16, 0, 0);
    }
    { // B: 256 chunks in 1 iter
      const int qb = (t & 192);
      const int q = qb + lane;
      const int r = q >> 2;
      const int c = (q & 3) ^ ((r >> 1) & 3);
      const short* gb = Bt + (size_t)(col0 + r) * K + k0 + c * 8;
      __builtin_amdgcn_global_load_lds((const __attribute__((address_space(1))) void*)gb,
                                       (__attribute__((address_space(3))) void*)&Bl[buf][qb * 8],
                                       16, 0, 0);
    }
  };

  stage(0, 0);
  __syncthreads();
  const int NK = K >> 5;
  int cur = 0;
  const int rA0 = wr * 64 + c16;
  const int rB0 = wc * 32 + c16;
  for (int kt = 0; kt < NK; ++kt) {
    if (kt + 1 < NK) stage(cur ^ 1, kt + 1);
    short8 aF[4], bF[2];
#pragma unroll
    for (int m = 0; m < 4; ++m) {
      const int r = rA0 + m * 16;
      const int c = g ^ ((r >> 1) & 3);
      aF[m] = *reinterpret_cast<const short8*>(&Al[cur][r * 32 + c * 8]);
    }
#pragma unroll
    for (int n = 0; n < 2; ++n) {
      const int r = rB0 + n * 16;
      const int c = g ^ ((r >> 1) & 3);
      bF[n] = *reinterpret_cast<const short8*>(&Bl[cur][r * 32 + c * 8]);
    }
#pragma unroll
    for (int m = 0; m < 4; ++m)
#pragma unroll
      for (int n = 0; n < 2; ++n)
        acc[m][n] = __builtin_amdgcn_mfma_f32_16x16x32_bf16(aF[m], bF[n], acc[m][n], 0, 0, 0);
    __syncthreads();
    cur ^= 1;
  }

  const int er = row0 + wr * 64 + g * 4;
  const int ec = col0 + wc * 32 + c16;
#pragma unroll
  for (int m = 0; m < 4; ++m)
#pragma unroll
    for (int n = 0; n < 2; ++n)
#pragma unroll
      for (int j = 0; j < 4; ++j) {
        const size_t off = (size_t)(er + m * 16 + j) * ldc + ec + n * 16;
        if (OUT_BF16)
          ((short*)Cout)[off] = f2bf(acc[m][n][j]);
        else
          ((float*)Cout)[off] = acc[m][n][j];
      }
}

// ---------------- fused causal attention with trigram geo bias ----------------
// r16 structure (banked: 40.0us attn / 108.9 total) + this round:
//  - row-sum via ones-MFMA into accS (deletes 2 shfl_xor + ~17 VALU/tile and
//    the 4 epilogue shfls; l lives in accS[j], same row layout as accO)
//  - s_setprio(1) around QK and PV MFMA clusters (T5)
//  - skip the final barrier (last tile stages nothing, epilogue is LDS-free)
__global__ __launch_bounds__(256) void attn_kernel(const short* __restrict__ qkvb,
                                                   const short* __restrict__ vT,
                                                   const float* __restrict__ head_scales,
                                                   const float* __restrict__ hdirs,
                                                   short* __restrict__ attnb) {
  __shared__ __align__(16) short Kl[2][64 * 128];
  __shared__ __align__(16) short Vl[2][128 * 64];
  __shared__ float kp_lds[2][64];

  const int bid = blockIdx.x;                       // 0..511
  const int bh = (bid & 7) * 4 + ((bid >> 3) & 3);  // 4 bh per XCD
  const int r2 = bid >> 5;                          // 0..15
  const int qt = (bid < 256) ? (15 - r2) : (r2 - 8); // balanced CU pairing
  const int b = bh >> 3, h = bh & 7;
  const int t = threadIdx.x, lane = t & 63, w = t >> 6;
  const int g = lane >> 4, c16 = lane & 15;
  const int q0w = qt * 64 + w * 16;
  const int q_abs = q0w + c16; // this lane's q row

  const short* qbase = qkvb + (size_t)(b * 1024) * 3072 + h * 128;
  const short* kbase = qbase + 1024;
  const short* vtb = vT + (size_t)bh * 128 * 1024;

  const float LOG2E = 1.44269504088896f;
  const float scale2 = 0.08838834764831845f * 1.44269504088896f; // /sqrt(128)*log2e
  const float d0 = hdirs[h * 3], d1 = hdirs[h * 3 + 1], d2 = hdirs[h * 3 + 2];
  const short8 ones8 = {(short)0x3F80, (short)0x3F80, (short)0x3F80, (short)0x3F80,
                        (short)0x3F80, (short)0x3F80, (short)0x3F80, (short)0x3F80};

  // Q fragments (B-operand): col = c16 (q row), k = kk*32 + g*8 .. +7
  short8 aQ[4];
  float hqp; // hs * qproj(row c16) * log2e
  {
    const short* qr = qbase + (size_t)(q0w + c16) * 3072;
#pragma unroll
    for (int kk = 0; kk < 4; ++kk)
      aQ[kk] = *reinterpret_cast<const short8*>(qr + kk * 32 + g * 8);
    const float hs = head_scales[h];
    hqp = hs * LOG2E * (b2f(qr[0]) * d0 + b2f(qr[1]) * d1 + b2f(qr[2]) * d2);
  }

  float m_s = -1e30f; // per q-row (= c16), replicated across g
  f32x4 accO[8];
  f32x4 accS = {0.0f, 0.0f, 0.0f, 0.0f}; // row-sum accumulator (D row = q = g*4+j)
#pragma unroll
  for (int d = 0; d < 8; ++d) {
    f32x4 z = {0.0f, 0.0f, 0.0f, 0.0f};
    accO[d] = z;
  }

  auto stageKV = [&](int buf, int kvt) {
    const int kv0 = kvt * 64;
#pragma unroll
    for (int i = 0; i < 4; ++i) {
      const int s = w * 4 + i;
      {
        const int r = s * 4 + g;            // kv row
        const int c = c16 ^ (r & 7);        // global 16B chunk (16/row)
        const short* ga = kbase + (size_t)(kv0 + r) * 3072 + c * 8;
        __builtin_amdgcn_global_load_lds((const __attribute__((address_space(1))) void*)ga,
                                         (__attribute__((address_space(3))) void*)&Kl[buf][s * 512],
                                         16, 0, 0);
      }
      {
        const int r = s * 8 + (lane >> 3);  // d row
        const int c = (lane & 7) ^ (r & 7); // global 16B chunk (8/row)
        const short* ga = vtb + (size_t)r * 1024 + kv0 + c * 8;
        __builtin_amdgcn_global_load_lds((const __attribute__((address_space(1))) void*)ga,
                                         (__attribute__((address_space(3))) void*)&Vl[buf][s * 512],
                                         16, 0, 0);
      }
    }
    // inline k-projection: 16 lanes/wave compute dot(K[row][0:3], dir)
    if (lane < 16) {
      const short* kr = kbase + (size_t)(kv0 + w * 16 + lane) * 3072;
      kp_lds[buf][w * 16 + lane] = b2f(kr[0]) * d0 + b2f(kr[1]) * d1 + b2f(kr[2]) * d2;
    }
  };

  const int nkv = qt + 1;
  stageKV(0, 0);
  __syncthreads();
  int cur = 0;
  for (int kvt = 0; kvt < nkv; ++kvt) {
    const int kv0 = kvt * 64;
    if (kvt + 1 < nkv) stageKV(cur ^ 1, kvt + 1); // prefetch overlaps compute
    const short* Kc = Kl[cur];
    const short* Vc = Vl[cur];
    const float* kpc = kp_lds[cur];
    const bool diag = (kvt == qt);
    const int nmax = diag ? (w + 1) : 4; // wave-uniform: n-blocks beyond are fully masked

    // ---- swapped QK^T: p[n][j] = P[k = n*16+g*4+j][q = c16] ----
    float p[4][4];
    __builtin_amdgcn_s_setprio(1);
#pragma unroll
    for (int n = 0; n < 4; ++n) {
      if (n >= nmax) {
        p[n][0] = -1e30f; p[n][1] = -1e30f; p[n][2] = -1e30f; p[n][3] = -1e30f;
        continue;
      }
      f32x4 s4 = {0.0f, 0.0f, 0.0f, 0.0f};
      const int r = n * 16 + c16; // kv row within tile (A-operand row)
#pragma unroll
      for (int kk = 0; kk < 4; ++kk) {
        const int cch = (kk * 4 + g) ^ (r & 7);
        short8 bK = *reinterpret_cast<const short8*>(&Kc[r * 128 + cch * 8]);
        s4 = __builtin_amdgcn_mfma_f32_16x16x32_bf16(bK, aQ[kk], s4, 0, 0, 0);
      }
      if (diag) {
#pragma unroll
        for (int j = 0; j < 4; ++j) {
          const int kloc = n * 16 + g * 4 + j;
          const float v = s4[j] * scale2 + hqp * kpc[kloc];
          p[n][j] = (kv0 + kloc <= q_abs) ? v : -1e30f;
        }
      } else {
#pragma unroll
        for (int j = 0; j < 4; ++j) {
          const int kloc = n * 16 + g * 4 + j;
          p[n][j] = s4[j] * scale2 + hqp * kpc[kloc];
        }
      }
    }
    __builtin_amdgcn_s_setprio(0);

    // ---- row max: in-register tree + 2 shfl_xor ----
    float mx;
    {
      float a0 = fmaxf(fmaxf(p[0][0], p[0][1]), fmaxf(p[0][2], p[0][3]));
      float a1 = fmaxf(fmaxf(p[1][0], p[1][1]), fmaxf(p[1][2], p[1][3]));
      float a2 = fmaxf(fmaxf(p[2][0], p[2][1]), fmaxf(p[2][2], p[2][3]));
      float a3 = fmaxf(fmaxf(p[3][0], p[3][1]), fmaxf(p[3][2], p[3][3]));
      mx = fmaxf(fmaxf(a0, a1), fmaxf(a2, a3));
      mx = fmaxf(mx, __shfl_xor(mx, 16, 64));
      mx = fmaxf(mx, __shfl_xor(mx, 32, 64));
    }

    // ---- defer-max (THR = 8 nats = 11.54 in log2 domain) ----
    if (__any(mx - m_s > 11.54f)) {
      const float mn = fmaxf(m_s, mx);
      const float alpha = exp2f(m_s - mn);
      m_s = mn;
      float aO[4];
#pragma unroll
      for (int j = 0; j < 4; ++j) aO[j] = __shfl(alpha, g * 4 + j, 64);
#pragma unroll
      for (int d = 0; d < 8; ++d)
#pragma unroll
        for (int j = 0; j < 4; ++j) accO[d][j] *= aO[j];
#pragma unroll
      for (int j = 0; j < 4; ++j) accS[j] *= aO[j];
    }

    // ---- exp2 (skipped n-blocks contribute 0; sum comes from ones-MFMA) ----
#pragma unroll
    for (int n = 0; n < 4; ++n) {
      if (n >= nmax) {
        p[n][0] = 0.0f; p[n][1] = 0.0f; p[n][2] = 0.0f; p[n][3] = 0.0f;
        continue;
      }
      p[n][0] = exp2f(p[n][0] - m_s);
      p[n][1] = exp2f(p[n][1] - m_s);
      p[n][2] = exp2f(p[n][2] - m_s);
      p[n][3] = exp2f(p[n][3] - m_s);
    }

    // ---- pack to bf16 pairs: pk[n][u] = {k = n*16+g*4+2u, +1} ----
    uint32_t pk[4][2];
#pragma unroll
    for (int n = 0; n < 4; ++n) {
      pk[n][0] = pack2bf(p[n][0], p[n][1]);
      pk[n][1] = pack2bf(p[n][2], p[n][3]);
    }

    // P columns k >= 32 are all zero iff nmax <= 2 -> skip aPu[1] + PV kk=1
    const int kkmax = (nmax <= 2) ? 1 : 2;

    // ---- redistribute to PV A-fragments: aP[kk] = P[q=c16][k=kk*32+g*8..+7] ----
    union { uint32_t d[4]; short8 s; } aPu[2];
#pragma unroll
    for (int kk = 0; kk < 2; ++kk) {
      if (kk >= kkmax) continue;
#pragma unroll
      for (int wd = 0; wd < 4; ++wd) {
        const int src = (2 * (g & 1) + (wd >> 1)) * 16 + c16;
        const uint32_t v0 = (uint32_t)__shfl((int)pk[kk * 2][wd & 1], src, 64);
        const uint32_t v1 = (uint32_t)__shfl((int)pk[kk * 2 + 1][wd & 1], src, 64);
        aPu[kk].d[wd] = (g >= 2) ? v1 : v0;
      }
    }

    // ---- PV + ones-MFMA row sum (D row = q = g*4+j, col = d = c16) ----
    __builtin_amdgcn_s_setprio(1);
    if (kkmax == 2) {
      accS = __builtin_amdgcn_mfma_f32_16x16x32_bf16(aPu[0].s, ones8, accS, 0, 0, 0);
      accS = __builtin_amdgcn_mfma_f32_16x16x32_bf16(aPu[1].s, ones8, accS, 0, 0, 0);
#pragma unroll
      for (int dt = 0; dt < 8; ++dt) {
        const int r = dt * 16 + c16; // d row in Vl
        const int c0x = (g) ^ (r & 7);
        const int c1x = (4 + g) ^ (r & 7);
        short8 bV0 = *reinterpret_cast<const short8*>(&Vc[r * 64 + c0x * 8]);
        short8 bV1 = *reinterpret_cast<const short8*>(&Vc[r * 64 + c1x * 8]);
        accO[dt] = __builtin_amdgcn_mfma_f32_16x16x32_bf16(aPu[0].s, bV0, accO[dt], 0, 0, 0);
        accO[dt] = __builtin_amdgcn_mfma_f32_16x16x32_bf16(aPu[1].s, bV1, accO[dt], 0, 0, 0);
      }
    } else {
      accS = __builtin_amdgcn_mfma_f32_16x16x32_bf16(aPu[0].s, ones8, accS, 0, 0, 0);
#pragma unroll
      for (int dt = 0; dt < 8; ++dt) {
        const int r = dt * 16 + c16;
        const int c0x = (g) ^ (r & 7);
        short8 bV0 = *reinterpret_cast<const short8*>(&Vc[r * 64 + c0x * 8]);
        accO[dt] = __builtin_amdgcn_mfma_f32_16x16x32_bf16(aPu[0].s, bV0, accO[dt], 0, 0, 0);
      }
    }
    __builtin_amdgcn_s_setprio(0);
    if (kvt + 1 < nkv) __syncthreads(); // next buffer staged + all waves done reading cur
    cur ^= 1;
  }

  // ---- epilogue: l is in accS[j] (same row layout as accO) ----
#pragma unroll
  for (int j = 0; j < 4; ++j) {
    const float linv = 1.0f / accS[j];
    const size_t rowoff = (size_t)(b * 1024 + q0w + g * 4 + j) * 1024 + h * 128;
#pragma unroll
    for (int dt = 0; dt < 8; ++dt)
      attnb[rowoff + dt * 16 + c16] = f2bf(accO[dt][j] * linv);
  }
}

extern "C" void kernel_launch(void* const* d_in, const int* in_sizes, int n_in,
                              void* d_out, int out_size, void* d_ws, size_t ws_size,
                              hipStream_t stream) {
  const float* x = (const float*)d_in[0];
  const float* Wqkv = (const float*)d_in[1];
  const float* Wout = (const float*)d_in[2];
  const float* hscale = (const float*)d_in[3];
  const float* hdirs = (const float*)d_in[4];
  float* out = (float*)d_out;

  char* ws = (char*)d_ws;
  short* xb = (short*)(ws);                                  // 8 MB (dead after gemm1)
  short* wqkvT = (short*)(ws + (size_t)8 * 1024 * 1024);     // 6 MB
  short* woutT = (short*)(ws + (size_t)14 * 1024 * 1024);    // 2 MB
  short* qkvb = (short*)(ws + (size_t)16 * 1024 * 1024);     // 24 MB
  short* vT = (short*)(ws + (size_t)40 * 1024 * 1024);       // 8 MB
  short* attnb = (short*)(ws + (size_t)48 * 1024 * 1024);    // 8 MB

  prep_kernel<<<6144, 256, 0, stream>>>(x, Wqkv, Wout, xb, wqkvT, woutT);
  gemm_kernel<1><<<dim3(24, 32), 256, 0, stream>>>(xb, wqkvT, (void*)qkvb, 1024, 3072);
  vtrans_kernel<<<1024, 256, 0, stream>>>(qkvb, vT);
  attn_kernel<<<512, 256, 0, stream>>>(qkvb, vT, hscale, hdirs, attnb);
  gemm64_kernel<0><<<dim3(16, 32), 256, 0, stream>>>(attnb, woutT, out, 1024, 1024);
}

// Round 18
// 107.562 us; speedup vs baseline: 1.0321x; 1.0321x over previous
//
#include <hip/hip_runtime.h>
#include <stdint.h>

typedef __attribute__((ext_vector_type(8))) short short8;
typedef __attribute__((ext_vector_type(4))) short short4v;
typedef __attribute__((ext_vector_type(4))) float f32x4;

__device__ __forceinline__ short f2bf(float x) {
  union { float f; uint32_t u; } c; c.f = x;
  uint32_t r = (c.u + 0x7FFFu + ((c.u >> 16) & 1u)) >> 16;
  return (short)r;
}
__device__ __forceinline__ float b2f(short s) {
  union { uint32_t u; float f; } c; c.u = ((uint32_t)(uint16_t)s) << 16;
  return c.f;
}
__device__ __forceinline__ uint32_t pack2bf(float lo, float hi) {
  return ((uint32_t)(uint16_t)f2bf(hi) << 16) | (uint32_t)(uint16_t)f2bf(lo);
}

// ============ merged prep: cvt(x) + tcvt(Wqkv) + tcvt(Wout) ============
__global__ __launch_bounds__(256) void prep_kernel(const float* __restrict__ x,
                                                   const float* __restrict__ Wqkv,
                                                   const float* __restrict__ Wout,
                                                   short* __restrict__ xb,
                                                   short* __restrict__ wqkvT,
                                                   short* __restrict__ woutT) {
  __shared__ __align__(16) short tile[32][33];
  const int bid = blockIdx.x;
  if (bid < 2048) {
    const int n4 = (4 * 1024 * 1024) / 4;
    int i = bid * 256 + threadIdx.x;
    for (; i < n4; i += 2048 * 256) {
      float4 v = reinterpret_cast<const float4*>(x)[i];
      short4v o;
      o.x = f2bf(v.x); o.y = f2bf(v.y); o.z = f2bf(v.z); o.w = f2bf(v.w);
      reinterpret_cast<short4v*>(xb)[i] = o;
    }
  } else {
    const float* in;
    short* out;
    int K, N, bx, by;
    if (bid < 2048 + 3072) {
      const int idx = bid - 2048;
      in = Wqkv; out = wqkvT; K = 1024; N = 3072; bx = idx % 96; by = idx / 96;
    } else {
      const int idx = bid - 5120;
      in = Wout; out = woutT; K = 1024; N = 1024; bx = idx % 32; by = idx / 32;
    }
    const int nb = bx * 32, kb = by * 32;
    const int tx = threadIdx.x & 31, ty = threadIdx.x >> 5; // 32 x 8
#pragma unroll
    for (int i = 0; i < 32; i += 8)
      tile[ty + i][tx] = f2bf(in[(size_t)(kb + ty + i) * N + nb + tx]);
    __syncthreads();
#pragma unroll
    for (int i = 0; i < 32; i += 8)
      out[(size_t)(nb + ty + i) * K + kb + tx] = tile[tx][ty + i];
  }
}

// ============ vtrans: qkv[b][kv][2048+c] -> vT[b][c][kv] ============
__global__ __launch_bounds__(256) void vtrans_kernel(const short* __restrict__ qkvb,
                                                     short* __restrict__ vT) {
  __shared__ __align__(16) short tile[64][65];
  const int bid = blockIdx.x;
  const int b = bid / 256;
  const int kv0 = (bid % 16) * 64, c0 = ((bid / 16) % 16) * 64;
  const int tx = threadIdx.x & 15, ty = threadIdx.x >> 4; // 16 x 16
  const short* src = qkvb + (size_t)(b * 1024) * 3072 + 2048;
#pragma unroll
  for (int i = 0; i < 64; i += 16) {
    int r = ty + i;
#pragma unroll
    for (int j = 0; j < 4; ++j)
      tile[r][tx * 4 + j] = src[(size_t)(kv0 + r) * 3072 + c0 + tx * 4 + j];
  }
  __syncthreads();
  short* dst = vT + (size_t)b * 1024 * 1024;
#pragma unroll
  for (int i = 0; i < 64; i += 16) {
    int cc = ty + i;
#pragma unroll
    for (int j = 0; j < 4; ++j)
      dst[(size_t)(c0 + cc) * 1024 + kv0 + tx * 4 + j] = tile[tx * 4 + j][cc];
  }
}

// -------- bf16 MFMA GEMM for qkv: C[M][N] = A[M][K]*Bt[N][K]^T, 128^2 tile --------
// 1-D grid 768, XCD-chunked bijective swizzle: xcd = wg&7 owns a 12x8 (bx,by)
// rectangle -> per-XCD L2 working set ~5MB (B 3MB + A 2MB), mostly resident.
template <int OUT_BF16>
__global__ __launch_bounds__(256) void gemm_kernel(const short* __restrict__ A,
                                                   const short* __restrict__ Bt,
                                                   void* __restrict__ Cout,
                                                   int K, int ldc) {
  __shared__ __align__(16) short Al[2][128 * 32];
  __shared__ __align__(16) short Bl[2][128 * 32];
  const int t = threadIdx.x;
  const int lane = t & 63, w = t >> 6;
  const int wr = w >> 1, wc = w & 1;
  const int g = lane >> 4, c16 = lane & 15;
  const int wg = blockIdx.x;
  const int xcd = wg & 7, ii = wg >> 3;            // ii in [0,96)
  const int bx = (xcd & 1) * 12 + (ii % 12);       // [0,24)
  const int by = (xcd >> 1) * 8 + (ii / 12);       // [0,32)
  const int row0 = by * 128, col0 = bx * 128;

  f32x4 acc[4][4];
#pragma unroll
  for (int m = 0; m < 4; ++m)
#pragma unroll
    for (int n = 0; n < 4; ++n) {
      f32x4 z = {0.0f, 0.0f, 0.0f, 0.0f};
      acc[m][n] = z;
    }

  auto stage = [&](int buf, int kt) {
    const int k0 = kt * 32;
#pragma unroll
    for (int i = 0; i < 2; ++i) {
      const int qb = i * 256 + (t & 192); // wave-uniform chunk base
      const int q = qb + lane;
      const int r = q >> 2;
      const int c = (q & 3) ^ ((r >> 1) & 3);
      const short* ga = A + (size_t)(row0 + r) * K + k0 + c * 8;
      const short* gb = Bt + (size_t)(col0 + r) * K + k0 + c * 8;
      __builtin_amdgcn_global_load_lds((const __attribute__((address_space(1))) void*)ga,
                                       (__attribute__((address_space(3))) void*)&Al[buf][qb * 8],
                                       16, 0, 0);
      __builtin_amdgcn_global_load_lds((const __attribute__((address_space(1))) void*)gb,
                                       (__attribute__((address_space(3))) void*)&Bl[buf][qb * 8],
                                       16, 0, 0);
    }
  };

  stage(0, 0);
  __syncthreads();
  const int NK = K >> 5;
  int cur = 0;
  const int rA0 = wr * 64 + c16;
  const int rB0 = wc * 64 + c16;
  for (int kt = 0; kt < NK; ++kt) {
    if (kt + 1 < NK) stage(cur ^ 1, kt + 1);
    short8 aF[4], bF[4];
#pragma unroll
    for (int m = 0; m < 4; ++m) {
      const int r = rA0 + m * 16;
      const int c = g ^ ((r >> 1) & 3);
      aF[m] = *reinterpret_cast<const short8*>(&Al[cur][r * 32 + c * 8]);
    }
#pragma unroll
    for (int n = 0; n < 4; ++n) {
      const int r = rB0 + n * 16;
      const int c = g ^ ((r >> 1) & 3);
      bF[n] = *reinterpret_cast<const short8*>(&Bl[cur][r * 32 + c * 8]);
    }
#pragma unroll
    for (int m = 0; m < 4; ++m)
#pragma unroll
      for (int n = 0; n < 4; ++n)
        acc[m][n] = __builtin_amdgcn_mfma_f32_16x16x32_bf16(aF[m], bF[n], acc[m][n], 0, 0, 0);
    __syncthreads();
    cur ^= 1;
  }

  const int er = row0 + wr * 64 + g * 4;
  const int ec = col0 + wc * 64 + c16;
#pragma unroll
  for (int m = 0; m < 4; ++m)
#pragma unroll
    for (int n = 0; n < 4; ++n)
#pragma unroll
      for (int j = 0; j < 4; ++j) {
        const size_t off = (size_t)(er + m * 16 + j) * ldc + ec + n * 16;
        if (OUT_BF16)
          ((short*)Cout)[off] = f2bf(acc[m][n][j]);
        else
          ((float*)Cout)[off] = acc[m][n][j];
      }
}

// ------------- bf16 MFMA GEMM: 128x64 tile (for small-N gemm2: 2x grid) -------------
template <int OUT_BF16>
__global__ __launch_bounds__(256) void gemm64_kernel(const short* __restrict__ A,
                                                     const short* __restrict__ Bt,
                                                     void* __restrict__ Cout,
                                                     int K, int ldc) {
  __shared__ __align__(16) short Al[2][128 * 32];
  __shared__ __align__(16) short Bl[2][64 * 32];
  const int t = threadIdx.x;
  const int lane = t & 63, w = t >> 6;
  const int wr = w >> 1, wc = w & 1;
  const int g = lane >> 4, c16 = lane & 15;
  const int row0 = blockIdx.y * 128, col0 = blockIdx.x * 64;

  f32x4 acc[4][2];
#pragma unroll
  for (int m = 0; m < 4; ++m)
#pragma unroll
    for (int n = 0; n < 2; ++n) {
      f32x4 z = {0.0f, 0.0f, 0.0f, 0.0f};
      acc[m][n] = z;
    }

  auto stage = [&](int buf, int kt) {
    const int k0 = kt * 32;
#pragma unroll
    for (int i = 0; i < 2; ++i) { // A: 512 chunks over 2 iters
      const int qb = i * 256 + (t & 192);
      const int q = qb + lane;
      const int r = q >> 2;
      const int c = (q & 3) ^ ((r >> 1) & 3);
      const short* ga = A + (size_t)(row0 + r) * K + k0 + c * 8;
      __builtin_amdgcn_global_load_lds((const __attribute__((address_space(1))) void*)ga,
                                       (__attribute__((address_space(3))) void*)&Al[buf][qb * 8],
                                       16, 0, 0);
    }
    { // B: 256 chunks in 1 iter
      const int qb = (t & 192);
      const int q = qb + lane;
      const int r = q >> 2;
      const int c = (q & 3) ^ ((r >> 1) & 3);
      const short* gb = Bt + (size_t)(col0 + r) * K + k0 + c * 8;
      __builtin_amdgcn_global_load_lds((const __attribute__((address_space(1))) void*)gb,
                                       (__attribute__((address_space(3))) void*)&Bl[buf][qb * 8],
                                       16, 0, 0);
    }
  };

  stage(0, 0);
  __syncthreads();
  const int NK = K >> 5;
  int cur = 0;
  const int rA0 = wr * 64 + c16;
  const int rB0 = wc * 32 + c16;
  for (int kt = 0; kt < NK; ++kt) {
    if (kt + 1 < NK) stage(cur ^ 1, kt + 1);
    short8 aF[4], bF[2];
#pragma unroll
    for (int m = 0; m < 4; ++m) {
      const int r = rA0 + m * 16;
      const int c = g ^ ((r >> 1) & 3);
      aF[m] = *reinterpret_cast<const short8*>(&Al[cur][r * 32 + c * 8]);
    }
#pragma unroll
    for (int n = 0; n < 2; ++n) {
      const int r = rB0 + n * 16;
      const int c = g ^ ((r >> 1) & 3);
      bF[n] = *reinterpret_cast<const short8*>(&Bl[cur][r * 32 + c * 8]);
    }
#pragma unroll
    for (int m = 0; m < 4; ++m)
#pragma unroll
      for (int n = 0; n < 2; ++n)
        acc[m][n] = __builtin_amdgcn_mfma_f32_16x16x32_bf16(aF[m], bF[n], acc[m][n], 0, 0, 0);
    __syncthreads();
    cur ^= 1;
  }

  const int er = row0 + wr * 64 + g * 4;
  const int ec = col0 + wc * 32 + c16;
#pragma unroll
  for (int m = 0; m < 4; ++m)
#pragma unroll
    for (int n = 0; n < 2; ++n)
#pragma unroll
      for (int j = 0; j < 4; ++j) {
        const size_t off = (size_t)(er + m * 16 + j) * ldc + ec + n * 16;
        if (OUT_BF16)
          ((short*)Cout)[off] = f2bf(acc[m][n][j]);
        else
          ((float*)Cout)[off] = acc[m][n][j];
      }
}

// ---------------- fused causal attention with trigram geo bias ----------------
// r16 structure verbatim (best measured: 39.9-40.1us attn): swapped-QK^T 16x16,
// in-register softmax, K+V double-buffered, one barrier/tile, inline kproj,
// diagonal-only mask + diagonal wave-skip (nmax=w+1, kkmax).
__global__ __launch_bounds__(256) void attn_kernel(const short* __restrict__ qkvb,
                                                   const short* __restrict__ vT,
                                                   const float* __restrict__ head_scales,
                                                   const float* __restrict__ hdirs,
                                                   short* __restrict__ attnb) {
  __shared__ __align__(16) short Kl[2][64 * 128];
  __shared__ __align__(16) short Vl[2][128 * 64];
  __shared__ float kp_lds[2][64];

  const int bid = blockIdx.x;                       // 0..511
  const int bh = (bid & 7) * 4 + ((bid >> 3) & 3);  // 4 bh per XCD
  const int r2 = bid >> 5;                          // 0..15
  const int qt = (bid < 256) ? (15 - r2) : (r2 - 8); // balanced CU pairing
  const int b = bh >> 3, h = bh & 7;
  const int t = threadIdx.x, lane = t & 63, w = t >> 6;
  const int g = lane >> 4, c16 = lane & 15;
  const int q0w = qt * 64 + w * 16;
  const int q_abs = q0w + c16; // this lane's q row

  const short* qbase = qkvb + (size_t)(b * 1024) * 3072 + h * 128;
  const short* kbase = qbase + 1024;
  const short* vtb = vT + (size_t)bh * 128 * 1024;

  const float LOG2E = 1.44269504088896f;
  const float scale2 = 0.08838834764831845f * 1.44269504088896f; // /sqrt(128)*log2e
  const float d0 = hdirs[h * 3], d1 = hdirs[h * 3 + 1], d2 = hdirs[h * 3 + 2];

  // Q fragments (B-operand): col = c16 (q row), k = kk*32 + g*8 .. +7
  short8 aQ[4];
  float hqp; // hs * qproj(row c16) * log2e
  {
    const short* qr = qbase + (size_t)(q0w + c16) * 3072;
#pragma unroll
    for (int kk = 0; kk < 4; ++kk)
      aQ[kk] = *reinterpret_cast<const short8*>(qr + kk * 32 + g * 8);
    const float hs = head_scales[h];
    hqp = hs * LOG2E * (b2f(qr[0]) * d0 + b2f(qr[1]) * d1 + b2f(qr[2]) * d2);
  }

  float m_s = -1e30f, l_s = 0.0f; // per q-row (= c16), replicated across g
  f32x4 accO[8];
#pragma unroll
  for (int d = 0; d < 8; ++d) {
    f32x4 z = {0.0f, 0.0f, 0.0f, 0.0f};
    accO[d] = z;
  }

  auto stageKV = [&](int buf, int kvt) {
    const int kv0 = kvt * 64;
#pragma unroll
    for (int i = 0; i < 4; ++i) {
      const int s = w * 4 + i;
      {
        const int r = s * 4 + g;            // kv row
        const int c = c16 ^ (r & 7);        // global 16B chunk (16/row)
        const short* ga = kbase + (size_t)(kv0 + r) * 3072 + c * 8;
        __builtin_amdgcn_global_load_lds((const __attribute__((address_space(1))) void*)ga,
                                         (__attribute__((address_space(3))) void*)&Kl[buf][s * 512],
                                         16, 0, 0);
      }
      {
        const int r = s * 8 + (lane >> 3);  // d row
        const int c = (lane & 7) ^ (r & 7); // global 16B chunk (8/row)
        const short* ga = vtb + (size_t)r * 1024 + kv0 + c * 8;
        __builtin_amdgcn_global_load_lds((const __attribute__((address_space(1))) void*)ga,
                                         (__attribute__((address_space(3))) void*)&Vl[buf][s * 512],
                                         16, 0, 0);
      }
    }
    // inline k-projection: 16 lanes/wave compute dot(K[row][0:3], dir)
    if (lane < 16) {
      const short* kr = kbase + (size_t)(kv0 + w * 16 + lane) * 3072;
      kp_lds[buf][w * 16 + lane] = b2f(kr[0]) * d0 + b2f(kr[1]) * d1 + b2f(kr[2]) * d2;
    }
  };

  const int nkv = qt + 1;
  stageKV(0, 0);
  __syncthreads();
  int cur = 0;
  for (int kvt = 0; kvt < nkv; ++kvt) {
    const int kv0 = kvt * 64;
    if (kvt + 1 < nkv) stageKV(cur ^ 1, kvt + 1); // prefetch overlaps compute
    const short* Kc = Kl[cur];
    const short* Vc = Vl[cur];
    const float* kpc = kp_lds[cur];
    const bool diag = (kvt == qt);
    const int nmax = diag ? (w + 1) : 4; // wave-uniform: n-blocks beyond are fully masked

    // ---- swapped QK^T: p[n][j] = P[k = n*16+g*4+j][q = c16] ----
    float p[4][4];
#pragma unroll
    for (int n = 0; n < 4; ++n) {
      if (n >= nmax) {
        p[n][0] = -1e30f; p[n][1] = -1e30f; p[n][2] = -1e30f; p[n][3] = -1e30f;
        continue;
      }
      f32x4 s4 = {0.0f, 0.0f, 0.0f, 0.0f};
      const int r = n * 16 + c16; // kv row within tile (A-operand row)
#pragma unroll
      for (int kk = 0; kk < 4; ++kk) {
        const int cch = (kk * 4 + g) ^ (r & 7);
        short8 bK = *reinterpret_cast<const short8*>(&Kc[r * 128 + cch * 8]);
        s4 = __builtin_amdgcn_mfma_f32_16x16x32_bf16(bK, aQ[kk], s4, 0, 0, 0);
      }
      if (diag) {
#pragma unroll
        for (int j = 0; j < 4; ++j) {
          const int kloc = n * 16 + g * 4 + j;
          const float v = s4[j] * scale2 + hqp * kpc[kloc];
          p[n][j] = (kv0 + kloc <= q_abs) ? v : -1e30f;
        }
      } else {
#pragma unroll
        for (int j = 0; j < 4; ++j) {
          const int kloc = n * 16 + g * 4 + j;
          p[n][j] = s4[j] * scale2 + hqp * kpc[kloc];
        }
      }
    }

    // ---- row max: in-register tree + 2 shfl_xor ----
    float mx;
    {
      float a0 = fmaxf(fmaxf(p[0][0], p[0][1]), fmaxf(p[0][2], p[0][3]));
      float a1 = fmaxf(fmaxf(p[1][0], p[1][1]), fmaxf(p[1][2], p[1][3]));
      float a2 = fmaxf(fmaxf(p[2][0], p[2][1]), fmaxf(p[2][2], p[2][3]));
      float a3 = fmaxf(fmaxf(p[3][0], p[3][1]), fmaxf(p[3][2], p[3][3]));
      mx = fmaxf(fmaxf(a0, a1), fmaxf(a2, a3));
      mx = fmaxf(mx, __shfl_xor(mx, 16, 64));
      mx = fmaxf(mx, __shfl_xor(mx, 32, 64));
    }

    // ---- defer-max (THR = 8 nats = 11.54 in log2 domain) ----
    if (__any(mx - m_s > 11.54f)) {
      const float mn = fmaxf(m_s, mx);
      const float alpha = exp2f(m_s - mn);
      m_s = mn;
      l_s *= alpha;
      float aO[4];
#pragma unroll
      for (int j = 0; j < 4; ++j) aO[j] = __shfl(alpha, g * 4 + j, 64);
#pragma unroll
      for (int d = 0; d < 8; ++d)
#pragma unroll
        for (int j = 0; j < 4; ++j) accO[d][j] *= aO[j];
    }

    // ---- exp2 + row sum (tree + 2 shfl_xor); skipped n-blocks contribute 0 ----
    float s01 = 0.0f, s23 = 0.0f;
#pragma unroll
    for (int n = 0; n < 4; ++n) {
      if (n >= nmax) {
        p[n][0] = 0.0f; p[n][1] = 0.0f; p[n][2] = 0.0f; p[n][3] = 0.0f;
        continue;
      }
      float e0 = exp2f(p[n][0] - m_s), e1 = exp2f(p[n][1] - m_s);
      float e2 = exp2f(p[n][2] - m_s), e3 = exp2f(p[n][3] - m_s);
      p[n][0] = e0; p[n][1] = e1; p[n][2] = e2; p[n][3] = e3;
      if (n < 2) s01 += (e0 + e1) + (e2 + e3); else s23 += (e0 + e1) + (e2 + e3);
    }
    float sum = s01 + s23;
    sum += __shfl_xor(sum, 16, 64);
    sum += __shfl_xor(sum, 32, 64);
    l_s += sum;

    // ---- pack to bf16 pairs: pk[n][u] = {k = n*16+g*4+2u, +1} ----
    uint32_t pk[4][2];
#pragma unroll
    for (int n = 0; n < 4; ++n) {
      pk[n][0] = pack2bf(p[n][0], p[n][1]);
      pk[n][1] = pack2bf(p[n][2], p[n][3]);
    }

    // P columns k >= 32 are all zero iff nmax <= 2 -> skip aPu[1] + PV kk=1
    const int kkmax = (nmax <= 2) ? 1 : 2;

    // ---- redistribute to PV A-fragments: aP[kk] = P[q=c16][k=kk*32+g*8..+7] ----
    union { uint32_t d[4]; short8 s; } aPu[2];
#pragma unroll
    for (int kk = 0; kk < 2; ++kk) {
      if (kk >= kkmax) continue;
#pragma unroll
      for (int wd = 0; wd < 4; ++wd) {
        const int src = (2 * (g & 1) + (wd >> 1)) * 16 + c16;
        const uint32_t v0 = (uint32_t)__shfl((int)pk[kk * 2][wd & 1], src, 64);
        const uint32_t v1 = (uint32_t)__shfl((int)pk[kk * 2 + 1][wd & 1], src, 64);
        aPu[kk].d[wd] = (g >= 2) ? v1 : v0;
      }
    }

    // ---- PV (D row = q = g*4+j, col = d = c16) ----
    if (kkmax == 2) {
#pragma unroll
      for (int dt = 0; dt < 8; ++dt) {
        const int r = dt * 16 + c16; // d row in Vl
        const int c0x = (g) ^ (r & 7);
        const int c1x = (4 + g) ^ (r & 7);
        short8 bV0 = *reinterpret_cast<const short8*>(&Vc[r * 64 + c0x * 8]);
        short8 bV1 = *reinterpret_cast<const short8*>(&Vc[r * 64 + c1x * 8]);
        accO[dt] = __builtin_amdgcn_mfma_f32_16x16x32_bf16(aPu[0].s, bV0, accO[dt], 0, 0, 0);
        accO[dt] = __builtin_amdgcn_mfma_f32_16x16x32_bf16(aPu[1].s, bV1, accO[dt], 0, 0, 0);
      }
    } else {
#pragma unroll
      for (int dt = 0; dt < 8; ++dt) {
        const int r = dt * 16 + c16;
        const int c0x = (g) ^ (r & 7);
        short8 bV0 = *reinterpret_cast<const short8*>(&Vc[r * 64 + c0x * 8]);
        accO[dt] = __builtin_amdgcn_mfma_f32_16x16x32_bf16(aPu[0].s, bV0, accO[dt], 0, 0, 0);
      }
    }
    __syncthreads(); // next buffer staged + all waves done reading cur
    cur ^= 1;
  }

  // ---- epilogue: fetch per-row 1/l via shfl, store bf16 [B,T,D] ----
  float linv[4];
#pragma unroll
  for (int j = 0; j < 4; ++j) linv[j] = 1.0f / __shfl(l_s, g * 4 + j, 64);
#pragma unroll
  for (int j = 0; j < 4; ++j) {
    const size_t rowoff = (size_t)(b * 1024 + q0w + g * 4 + j) * 1024 + h * 128;
#pragma unroll
    for (int dt = 0; dt < 8; ++dt)
      attnb[rowoff + dt * 16 + c16] = f2bf(accO[dt][j] * linv[j]);
  }
}

extern "C" void kernel_launch(void* const* d_in, const int* in_sizes, int n_in,
                              void* d_out, int out_size, void* d_ws, size_t ws_size,
                              hipStream_t stream) {
  const float* x = (const float*)d_in[0];
  const float* Wqkv = (const float*)d_in[1];
  const float* Wout = (const float*)d_in[2];
  const float* hscale = (const float*)d_in[3];
  const float* hdirs = (const float*)d_in[4];
  float* out = (float*)d_out;

  char* ws = (char*)d_ws;
  short* xb = (short*)(ws);                                  // 8 MB (dead after gemm1)
  short* wqkvT = (short*)(ws + (size_t)8 * 1024 * 1024);     // 6 MB
  short* woutT = (short*)(ws + (size_t)14 * 1024 * 1024);    // 2 MB
  short* qkvb = (short*)(ws + (size_t)16 * 1024 * 1024);     // 24 MB
  short* vT = (short*)(ws + (size_t)40 * 1024 * 1024);       // 8 MB
  short* attnb = (short*)(ws + (size_t)48 * 1024 * 1024);    // 8 MB

  prep_kernel<<<6144, 256, 0, stream>>>(x, Wqkv, Wout, xb, wqkvT, woutT);
  gemm_kernel<1><<<768, 256, 0, stream>>>(xb, wqkvT, (void*)qkvb, 1024, 3072);
  vtrans_kernel<<<1024, 256, 0, stream>>>(qkvb, vT);
  attn_kernel<<<512, 256, 0, stream>>>(qkvb, vT, hscale, hdirs, attnb);
  gemm64_kernel<0><<<dim3(16, 32), 256, 0, stream>>>(attnb, woutT, out, 1024, 1024);
}

// Round 19
// 98.680 us; speedup vs baseline: 1.1250x; 1.0900x over previous
//
#include <hip/hip_runtime.h>
#include <stdint.h>

typedef __attribute__((ext_vector_type(8))) short short8;
typedef __attribute__((ext_vector_type(4))) short short4v;
typedef __attribute__((ext_vector_type(4))) float f32x4;

__device__ __forceinline__ short f2bf(float x) {
  union { float f; uint32_t u; } c; c.f = x;
  uint32_t r = (c.u + 0x7FFFu + ((c.u >> 16) & 1u)) >> 16;
  return (short)r;
}
__device__ __forceinline__ float b2f(short s) {
  union { uint32_t u; float f; } c; c.u = ((uint32_t)(uint16_t)s) << 16;
  return c.f;
}
__device__ __forceinline__ uint32_t pack2bf(float lo, float hi) {
  return ((uint32_t)(uint16_t)f2bf(hi) << 16) | (uint32_t)(uint16_t)f2bf(lo);
}

// ============ merged prep: cvt(x) + tcvt(Wqkv) + tcvt(Wout) ============
__global__ __launch_bounds__(256) void prep_kernel(const float* __restrict__ x,
                                                   const float* __restrict__ Wqkv,
                                                   const float* __restrict__ Wout,
                                                   short* __restrict__ xb,
                                                   short* __restrict__ wqkvT,
                                                   short* __restrict__ woutT) {
  __shared__ __align__(16) short tile[32][33];
  const int bid = blockIdx.x;
  if (bid < 2048) {
    const int n4 = (4 * 1024 * 1024) / 4;
    int i = bid * 256 + threadIdx.x;
    for (; i < n4; i += 2048 * 256) {
      float4 v = reinterpret_cast<const float4*>(x)[i];
      short4v o;
      o.x = f2bf(v.x); o.y = f2bf(v.y); o.z = f2bf(v.z); o.w = f2bf(v.w);
      reinterpret_cast<short4v*>(xb)[i] = o;
    }
  } else {
    const float* in;
    short* out;
    int K, N, bx, by;
    if (bid < 2048 + 3072) {
      const int idx = bid - 2048;
      in = Wqkv; out = wqkvT; K = 1024; N = 3072; bx = idx % 96; by = idx / 96;
    } else {
      const int idx = bid - 5120;
      in = Wout; out = woutT; K = 1024; N = 1024; bx = idx % 32; by = idx / 32;
    }
    const int nb = bx * 32, kb = by * 32;
    const int tx = threadIdx.x & 31, ty = threadIdx.x >> 5; // 32 x 8
#pragma unroll
    for (int i = 0; i < 32; i += 8)
      tile[ty + i][tx] = f2bf(in[(size_t)(kb + ty + i) * N + nb + tx]);
    __syncthreads();
#pragma unroll
    for (int i = 0; i < 32; i += 8)
      out[(size_t)(nb + ty + i) * K + kb + tx] = tile[tx][ty + i];
  }
}

// -------- bf16 MFMA GEMM for qkv: C[M][N] = A[M][K]*Bt[N][K]^T, 128^2 tile --------
// 1-D grid 768, XCD-chunked bijective swizzle (12x8 rectangle per XCD).
// V-region tiles (col0 >= 2048) write DIRECTLY to vT transposed via an LDS
// round-trip (vtrans kernel eliminated); other tiles write qkvb as before.
__global__ __launch_bounds__(256) void gemm_kernel(const short* __restrict__ A,
                                                   const short* __restrict__ Bt,
                                                   short* __restrict__ Cout,
                                                   short* __restrict__ vTout,
                                                   int K, int ldc) {
  __shared__ __align__(16) union {
    struct { short Al[2][128 * 32]; short Bl[2][128 * 32]; } g;
    short T[128 * 128]; // transpose buffer [c128][t128], 16B-chunk XOR swizzle
  } sm;
  const int t = threadIdx.x;
  const int lane = t & 63, w = t >> 6;
  const int wr = w >> 1, wc = w & 1;
  const int g = lane >> 4, c16 = lane & 15;
  const int wg = blockIdx.x;
  const int xcd = wg & 7, ii = wg >> 3;            // ii in [0,96)
  const int bx = (xcd & 1) * 12 + (ii % 12);       // [0,24)
  const int by = (xcd >> 1) * 8 + (ii / 12);       // [0,32)
  const int row0 = by * 128, col0 = bx * 128;

  f32x4 acc[4][4];
#pragma unroll
  for (int m = 0; m < 4; ++m)
#pragma unroll
    for (int n = 0; n < 4; ++n) {
      f32x4 z = {0.0f, 0.0f, 0.0f, 0.0f};
      acc[m][n] = z;
    }

  auto stage = [&](int buf, int kt) {
    const int k0 = kt * 32;
#pragma unroll
    for (int i = 0; i < 2; ++i) {
      const int qb = i * 256 + (t & 192); // wave-uniform chunk base
      const int q = qb + lane;
      const int r = q >> 2;
      const int c = (q & 3) ^ ((r >> 1) & 3);
      const short* ga = A + (size_t)(row0 + r) * K + k0 + c * 8;
      const short* gb = Bt + (size_t)(col0 + r) * K + k0 + c * 8;
      __builtin_amdgcn_global_load_lds((const __attribute__((address_space(1))) void*)ga,
                                       (__attribute__((address_space(3))) void*)&sm.g.Al[buf][qb * 8],
                                       16, 0, 0);
      __builtin_amdgcn_global_load_lds((const __attribute__((address_space(1))) void*)gb,
                                       (__attribute__((address_space(3))) void*)&sm.g.Bl[buf][qb * 8],
                                       16, 0, 0);
    }
  };

  stage(0, 0);
  __syncthreads();
  const int NK = K >> 5;
  int cur = 0;
  const int rA0 = wr * 64 + c16;
  const int rB0 = wc * 64 + c16;
  for (int kt = 0; kt < NK; ++kt) {
    if (kt + 1 < NK) stage(cur ^ 1, kt + 1);
    short8 aF[4], bF[4];
#pragma unroll
    for (int m = 0; m < 4; ++m) {
      const int r = rA0 + m * 16;
      const int c = g ^ ((r >> 1) & 3);
      aF[m] = *reinterpret_cast<const short8*>(&sm.g.Al[cur][r * 32 + c * 8]);
    }
#pragma unroll
    for (int n = 0; n < 4; ++n) {
      const int r = rB0 + n * 16;
      const int c = g ^ ((r >> 1) & 3);
      bF[n] = *reinterpret_cast<const short8*>(&sm.g.Bl[cur][r * 32 + c * 8]);
    }
#pragma unroll
    for (int m = 0; m < 4; ++m)
#pragma unroll
      for (int n = 0; n < 4; ++n)
        acc[m][n] = __builtin_amdgcn_mfma_f32_16x16x32_bf16(aF[m], bF[n], acc[m][n], 0, 0, 0);
    __syncthreads();
    cur ^= 1;
  }

  if (col0 < 2048) {
    // ---- Q/K region: normal bf16 store to qkvb ----
    const int er = row0 + wr * 64 + g * 4;
    const int ec = col0 + wc * 64 + c16;
#pragma unroll
    for (int m = 0; m < 4; ++m)
#pragma unroll
      for (int n = 0; n < 4; ++n)
#pragma unroll
        for (int j = 0; j < 4; ++j)
          Cout[(size_t)(er + m * 16 + j) * ldc + ec + n * 16] = f2bf(acc[m][n][j]);
  } else {
    // ---- V region: transpose via LDS, store to vT[b][c][t] ----
    // phase 1: T[c128][t128] with 16B-chunk swizzle chunk' = chunk ^ (c128&7)
#pragma unroll
    for (int m = 0; m < 4; ++m) {
      const int t128 = wr * 64 + m * 16 + g * 4;        // 4-aligned
      const int chunk = t128 >> 3, half = (t128 >> 2) & 1;
#pragma unroll
      for (int n = 0; n < 4; ++n) {
        const int c128 = wc * 64 + n * 16 + c16;
        short4v v4;
        v4.x = f2bf(acc[m][n][0]); v4.y = f2bf(acc[m][n][1]);
        v4.z = f2bf(acc[m][n][2]); v4.w = f2bf(acc[m][n][3]);
        const int off = c128 * 128 + ((chunk ^ (c128 & 7)) << 3) + half * 4; // shorts
        *reinterpret_cast<short4v*>(&sm.T[off]) = v4;
      }
    }
    __syncthreads();
    // phase 2: coalesced 16B row reads -> contiguous vT stores
    const int b = by >> 3, tt0 = (by & 7) * 128;
    const int cv0 = col0 - 2048;
    short* dst = vTout + (size_t)b * 1024 * 1024 + tt0;
#pragma unroll
    for (int it = 0; it < 8; ++it) {
      const int idx = it * 256 + t;
      const int row = idx >> 4, seg = idx & 15;
      short8 v = *reinterpret_cast<const short8*>(&sm.T[row * 128 + ((seg ^ (row & 7)) << 3)]);
      *reinterpret_cast<short8*>(&dst[(size_t)(cv0 + row) * 1024 + seg * 8]) = v;
    }
  }
}

// ------------- bf16 MFMA GEMM: 128x64 tile, XCD-chunked (gemm2) -------------
// 1-D grid 512: xcd = wg&7 owns by in [4*xcd, 4*xcd+4) x all 16 bx
// -> per-XCD working set A 1MB + B 2MB (L2-resident).
template <int OUT_BF16>
__global__ __launch_bounds__(256) void gemm64_kernel(const short* __restrict__ A,
                                                     const short* __restrict__ Bt,
                                                     void* __restrict__ Cout,
                                                     int K, int ldc) {
  __shared__ __align__(16) short Al[2][128 * 32];
  __shared__ __align__(16) short Bl[2][64 * 32];
  const int t = threadIdx.x;
  const int lane = t & 63, w = t >> 6;
  const int wr = w >> 1, wc = w & 1;
  const int g = lane >> 4, c16 = lane & 15;
  const int wg = blockIdx.x;
  const int xcd = wg & 7, ii = wg >> 3;        // ii in [0,64)
  const int by = xcd * 4 + (ii >> 4);          // [0,32)
  const int bx = ii & 15;                      // [0,16)
  const int row0 = by * 128, col0 = bx * 64;

  f32x4 acc[4][2];
#pragma unroll
  for (int m = 0; m < 4; ++m)
#pragma unroll
    for (int n = 0; n < 2; ++n) {
      f32x4 z = {0.0f, 0.0f, 0.0f, 0.0f};
      acc[m][n] = z;
    }

  auto stage = [&](int buf, int kt) {
    const int k0 = kt * 32;
#pragma unroll
    for (int i = 0; i < 2; ++i) { // A: 512 chunks over 2 iters
      const int qb = i * 256 + (t & 192);
      const int q = qb + lane;
      const int r = q >> 2;
      const int c = (q & 3) ^ ((r >> 1) & 3);
      const short* ga = A + (size_t)(row0 + r) * K + k0 + c * 8;
      __builtin_amdgcn_global_load_lds((const __attribute__((address_space(1))) void*)ga,
                                       (__attribute__((address_space(3))) void*)&Al[buf][qb * 8],
                                       16, 0, 0);
    }
    { // B: 256 chunks in 1 iter
      const int qb = (t & 192);
      const int q = qb + lane;
      const int r = q >> 2;
      const int c = (q & 3) ^ ((r >> 1) & 3);
      const short* gb = Bt + (size_t)(col0 + r) * K + k0 + c * 8;
      __builtin_amdgcn_global_load_lds((const __attribute__((address_space(1))) void*)gb,
                                       (__attribute__((address_space(3))) void*)&Bl[buf][qb * 8],
                                       16, 0, 0);
    }
  };

  stage(0, 0);
  __syncthreads();
  const int NK = K >> 5;
  int cur = 0;
  const int rA0 = wr * 64 + c16;
  const int rB0 = wc * 32 + c16;
  for (int kt = 0; kt < NK; ++kt) {
    if (kt + 1 < NK) stage(cur ^ 1, kt + 1);
    short8 aF[4], bF[2];
#pragma unroll
    for (int m = 0; m < 4; ++m) {
      const int r = rA0 + m * 16;
      const int c = g ^ ((r >> 1) & 3);
      aF[m] = *reinterpret_cast<const short8*>(&Al[cur][r * 32 + c * 8]);
    }
#pragma unroll
    for (int n = 0; n < 2; ++n) {
      const int r = rB0 + n * 16;
      const int c = g ^ ((r >> 1) & 3);
      bF[n] = *reinterpret_cast<const short8*>(&Bl[cur][r * 32 + c * 8]);
    }
#pragma unroll
    for (int m = 0; m < 4; ++m)
#pragma unroll
      for (int n = 0; n < 2; ++n)
        acc[m][n] = __builtin_amdgcn_mfma_f32_16x16x32_bf16(aF[m], bF[n], acc[m][n], 0, 0, 0);
    __syncthreads();
    cur ^= 1;
  }

  const int er = row0 + wr * 64 + g * 4;
  const int ec = col0 + wc * 32 + c16;
#pragma unroll
  for (int m = 0; m < 4; ++m)
#pragma unroll
    for (int n = 0; n < 2; ++n)
#pragma unroll
      for (int j = 0; j < 4; ++j) {
        const size_t off = (size_t)(er + m * 16 + j) * ldc + ec + n * 16;
        if (OUT_BF16)
          ((short*)Cout)[off] = f2bf(acc[m][n][j]);
        else
          ((float*)Cout)[off] = acc[m][n][j];
      }
}

// ---------------- fused causal attention with trigram geo bias ----------------
// r16 structure verbatim (best measured: 39.9-40.1us attn).
__global__ __launch_bounds__(256) void attn_kernel(const short* __restrict__ qkvb,
                                                   const short* __restrict__ vT,
                                                   const float* __restrict__ head_scales,
                                                   const float* __restrict__ hdirs,
                                                   short* __restrict__ attnb) {
  __shared__ __align__(16) short Kl[2][64 * 128];
  __shared__ __align__(16) short Vl[2][128 * 64];
  __shared__ float kp_lds[2][64];

  const int bid = blockIdx.x;                       // 0..511
  const int bh = (bid & 7) * 4 + ((bid >> 3) & 3);  // 4 bh per XCD
  const int r2 = bid >> 5;                          // 0..15
  const int qt = (bid < 256) ? (15 - r2) : (r2 - 8); // balanced CU pairing
  const int b = bh >> 3, h = bh & 7;
  const int t = threadIdx.x, lane = t & 63, w = t >> 6;
  const int g = lane >> 4, c16 = lane & 15;
  const int q0w = qt * 64 + w * 16;
  const int q_abs = q0w + c16; // this lane's q row

  const short* qbase = qkvb + (size_t)(b * 1024) * 3072 + h * 128;
  const short* kbase = qbase + 1024;
  const short* vtb = vT + (size_t)bh * 128 * 1024;

  const float LOG2E = 1.44269504088896f;
  const float scale2 = 0.08838834764831845f * 1.44269504088896f; // /sqrt(128)*log2e
  const float d0 = hdirs[h * 3], d1 = hdirs[h * 3 + 1], d2 = hdirs[h * 3 + 2];

  // Q fragments (B-operand): col = c16 (q row), k = kk*32 + g*8 .. +7
  short8 aQ[4];
  float hqp; // hs * qproj(row c16) * log2e
  {
    const short* qr = qbase + (size_t)(q0w + c16) * 3072;
#pragma unroll
    for (int kk = 0; kk < 4; ++kk)
      aQ[kk] = *reinterpret_cast<const short8*>(qr + kk * 32 + g * 8);
    const float hs = head_scales[h];
    hqp = hs * LOG2E * (b2f(qr[0]) * d0 + b2f(qr[1]) * d1 + b2f(qr[2]) * d2);
  }

  float m_s = -1e30f, l_s = 0.0f; // per q-row (= c16), replicated across g
  f32x4 accO[8];
#pragma unroll
  for (int d = 0; d < 8; ++d) {
    f32x4 z = {0.0f, 0.0f, 0.0f, 0.0f};
    accO[d] = z;
  }

  auto stageKV = [&](int buf, int kvt) {
    const int kv0 = kvt * 64;
#pragma unroll
    for (int i = 0; i < 4; ++i) {
      const int s = w * 4 + i;
      {
        const int r = s * 4 + g;            // kv row
        const int c = c16 ^ (r & 7);        // global 16B chunk (16/row)
        const short* ga = kbase + (size_t)(kv0 + r) * 3072 + c * 8;
        __builtin_amdgcn_global_load_lds((const __attribute__((address_space(1))) void*)ga,
                                         (__attribute__((address_space(3))) void*)&Kl[buf][s * 512],
                                         16, 0, 0);
      }
      {
        const int r = s * 8 + (lane >> 3);  // d row
        const int c = (lane & 7) ^ (r & 7); // global 16B chunk (8/row)
        const short* ga = vtb + (size_t)r * 1024 + kv0 + c * 8;
        __builtin_amdgcn_global_load_lds((const __attribute__((address_space(1))) void*)ga,
                                         (__attribute__((address_space(3))) void*)&Vl[buf][s * 512],
                                         16, 0, 0);
      }
    }
    // inline k-projection: 16 lanes/wave compute dot(K[row][0:3], dir)
    if (lane < 16) {
      const short* kr = kbase + (size_t)(kv0 + w * 16 + lane) * 3072;
      kp_lds[buf][w * 16 + lane] = b2f(kr[0]) * d0 + b2f(kr[1]) * d1 + b2f(kr[2]) * d2;
    }
  };

  const int nkv = qt + 1;
  stageKV(0, 0);
  __syncthreads();
  int cur = 0;
  for (int kvt = 0; kvt < nkv; ++kvt) {
    const int kv0 = kvt * 64;
    if (kvt + 1 < nkv) stageKV(cur ^ 1, kvt + 1); // prefetch overlaps compute
    const short* Kc = Kl[cur];
    const short* Vc = Vl[cur];
    const float* kpc = kp_lds[cur];
    const bool diag = (kvt == qt);
    const int nmax = diag ? (w + 1) : 4; // wave-uniform: n-blocks beyond are fully masked

    // ---- swapped QK^T: p[n][j] = P[k = n*16+g*4+j][q = c16] ----
    float p[4][4];
#pragma unroll
    for (int n = 0; n < 4; ++n) {
      if (n >= nmax) {
        p[n][0] = -1e30f; p[n][1] = -1e30f; p[n][2] = -1e30f; p[n][3] = -1e30f;
        continue;
      }
      f32x4 s4 = {0.0f, 0.0f, 0.0f, 0.0f};
      const int r = n * 16 + c16; // kv row within tile (A-operand row)
#pragma unroll
      for (int kk = 0; kk < 4; ++kk) {
        const int cch = (kk * 4 + g) ^ (r & 7);
        short8 bK = *reinterpret_cast<const short8*>(&Kc[r * 128 + cch * 8]);
        s4 = __builtin_amdgcn_mfma_f32_16x16x32_bf16(bK, aQ[kk], s4, 0, 0, 0);
      }
      if (diag) {
#pragma unroll
        for (int j = 0; j < 4; ++j) {
          const int kloc = n * 16 + g * 4 + j;
          const float v = s4[j] * scale2 + hqp * kpc[kloc];
          p[n][j] = (kv0 + kloc <= q_abs) ? v : -1e30f;
        }
      } else {
#pragma unroll
        for (int j = 0; j < 4; ++j) {
          const int kloc = n * 16 + g * 4 + j;
          p[n][j] = s4[j] * scale2 + hqp * kpc[kloc];
        }
      }
    }

    // ---- row max: in-register tree + 2 shfl_xor ----
    float mx;
    {
      float a0 = fmaxf(fmaxf(p[0][0], p[0][1]), fmaxf(p[0][2], p[0][3]));
      float a1 = fmaxf(fmaxf(p[1][0], p[1][1]), fmaxf(p[1][2], p[1][3]));
      float a2 = fmaxf(fmaxf(p[2][0], p[2][1]), fmaxf(p[2][2], p[2][3]));
      float a3 = fmaxf(fmaxf(p[3][0], p[3][1]), fmaxf(p[3][2], p[3][3]));
      mx = fmaxf(fmaxf(a0, a1), fmaxf(a2, a3));
      mx = fmaxf(mx, __shfl_xor(mx, 16, 64));
      mx = fmaxf(mx, __shfl_xor(mx, 32, 64));
    }

    // ---- defer-max (THR = 8 nats = 11.54 in log2 domain) ----
    if (__any(mx - m_s > 11.54f)) {
      const float mn = fmaxf(m_s, mx);
      const float alpha = exp2f(m_s - mn);
      m_s = mn;
      l_s *= alpha;
      float aO[4];
#pragma unroll
      for (int j = 0; j < 4; ++j) aO[j] = __shfl(alpha, g * 4 + j, 64);
#pragma unroll
      for (int d = 0; d < 8; ++d)
#pragma unroll
        for (int j = 0; j < 4; ++j) accO[d][j] *= aO[j];
    }

    // ---- exp2 + row sum (tree + 2 shfl_xor); skipped n-blocks contribute 0 ----
    float s01 = 0.0f, s23 = 0.0f;
#pragma unroll
    for (int n = 0; n < 4; ++n) {
      if (n >= nmax) {
        p[n][0] = 0.0f; p[n][1] = 0.0f; p[n][2] = 0.0f; p[n][3] = 0.0f;
        continue;
      }
      float e0 = exp2f(p[n][0] - m_s), e1 = exp2f(p[n][1] - m_s);
      float e2 = exp2f(p[n][2] - m_s), e3 = exp2f(p[n][3] - m_s);
      p[n][0] = e0; p[n][1] = e1; p[n][2] = e2; p[n][3] = e3;
      if (n < 2) s01 += (e0 + e1) + (e2 + e3); else s23 += (e0 + e1) + (e2 + e3);
    }
    float sum = s01 + s23;
    sum += __shfl_xor(sum, 16, 64);
    sum += __shfl_xor(sum, 32, 64);
    l_s += sum;

    // ---- pack to bf16 pairs: pk[n][u] = {k = n*16+g*4+2u, +1} ----
    uint32_t pk[4][2];
#pragma unroll
    for (int n = 0; n < 4; ++n) {
      pk[n][0] = pack2bf(p[n][0], p[n][1]);
      pk[n][1] = pack2bf(p[n][2], p[n][3]);
    }

    // P columns k >= 32 are all zero iff nmax <= 2 -> skip aPu[1] + PV kk=1
    const int kkmax = (nmax <= 2) ? 1 : 2;

    // ---- redistribute to PV A-fragments: aP[kk] = P[q=c16][k=kk*32+g*8..+7] ----
    union { uint32_t d[4]; short8 s; } aPu[2];
#pragma unroll
    for (int kk = 0; kk < 2; ++kk) {
      if (kk >= kkmax) continue;
#pragma unroll
      for (int wd = 0; wd < 4; ++wd) {
        const int src = (2 * (g & 1) + (wd >> 1)) * 16 + c16;
        const uint32_t v0 = (uint32_t)__shfl((int)pk[kk * 2][wd & 1], src, 64);
        const uint32_t v1 = (uint32_t)__shfl((int)pk[kk * 2 + 1][wd & 1], src, 64);
        aPu[kk].d[wd] = (g >= 2) ? v1 : v0;
      }
    }

    // ---- PV (D row = q = g*4+j, col = d = c16) ----
    if (kkmax == 2) {
#pragma unroll
      for (int dt = 0; dt < 8; ++dt) {
        const int r = dt * 16 + c16; // d row in Vl
        const int c0x = (g) ^ (r & 7);
        const int c1x = (4 + g) ^ (r & 7);
        short8 bV0 = *reinterpret_cast<const short8*>(&Vc[r * 64 + c0x * 8]);
        short8 bV1 = *reinterpret_cast<const short8*>(&Vc[r * 64 + c1x * 8]);
        accO[dt] = __builtin_amdgcn_mfma_f32_16x16x32_bf16(aPu[0].s, bV0, accO[dt], 0, 0, 0);
        accO[dt] = __builtin_amdgcn_mfma_f32_16x16x32_bf16(aPu[1].s, bV1, accO[dt], 0, 0, 0);
      }
    } else {
#pragma unroll
      for (int dt = 0; dt < 8; ++dt) {
        const int r = dt * 16 + c16;
        const int c0x = (g) ^ (r & 7);
        short8 bV0 = *reinterpret_cast<const short8*>(&Vc[r * 64 + c0x * 8]);
        accO[dt] = __builtin_amdgcn_mfma_f32_16x16x32_bf16(aPu[0].s, bV0, accO[dt], 0, 0, 0);
      }
    }
    __syncthreads(); // next buffer staged + all waves done reading cur
    cur ^= 1;
  }

  // ---- epilogue: fetch per-row 1/l via shfl, store bf16 [B,T,D] ----
  float linv[4];
#pragma unroll
  for (int j = 0; j < 4; ++j) linv[j] = 1.0f / __shfl(l_s, g * 4 + j, 64);
#pragma unroll
  for (int j = 0; j < 4; ++j) {
    const size_t rowoff = (size_t)(b * 1024 + q0w + g * 4 + j) * 1024 + h * 128;
#pragma unroll
    for (int dt = 0; dt < 8; ++dt)
      attnb[rowoff + dt * 16 + c16] = f2bf(accO[dt][j] * linv[j]);
  }
}

extern "C" void kernel_launch(void* const* d_in, const int* in_sizes, int n_in,
                              void* d_out, int out_size, void* d_ws, size_t ws_size,
                              hipStream_t stream) {
  const float* x = (const float*)d_in[0];
  const float* Wqkv = (const float*)d_in[1];
  const float* Wout = (const float*)d_in[2];
  const float* hscale = (const float*)d_in[3];
  const float* hdirs = (const float*)d_in[4];
  float* out = (float*)d_out;

  char* ws = (char*)d_ws;
  short* xb = (short*)(ws);                                  // 8 MB (dead after gemm1)
  short* wqkvT = (short*)(ws + (size_t)8 * 1024 * 1024);     // 6 MB
  short* woutT = (short*)(ws + (size_t)14 * 1024 * 1024);    // 2 MB
  short* qkvb = (short*)(ws + (size_t)16 * 1024 * 1024);     // 24 MB (V region unused)
  short* vT = (short*)(ws + (size_t)40 * 1024 * 1024);       // 8 MB
  short* attnb = (short*)(ws + (size_t)48 * 1024 * 1024);    // 8 MB

  prep_kernel<<<6144, 256, 0, stream>>>(x, Wqkv, Wout, xb, wqkvT, woutT);
  gemm_kernel<<<768, 256, 0, stream>>>(xb, wqkvT, qkvb, vT, 1024, 3072);
  attn_kernel<<<512, 256, 0, stream>>>(qkvb, vT, hscale, hdirs, attnb);
  gemm64_kernel<0><<<512, 256, 0, stream>>>(attnb, woutT, out, 1024, 1024);
}